// Round 1
// baseline (291.897 us; speedup 1.0000x reference)
//
#include <hip/hip_runtime.h>

// B=16, K=32, H=W=28, HID=OUT=64, NOPS=8
// ws layout (floats): h1[512*6272] h2[512*3136] feat[512*64] s[16*64] t7c[16*64]
//                     x8[16*64] Wt[8*64*64]

// ---------------- k1: conv1 (1->32, 3x3 SAME) + ReLU + maxpool2 ----------------
__global__ __launch_bounds__(256) void k1_conv1(const float* __restrict__ x,
    const float* __restrict__ w, const float* __restrict__ bias,
    float* __restrict__ h1) {
  __shared__ float si[30*30];
  __shared__ float sw[32*9];
  __shared__ float sb[32];
  const int n = blockIdx.x, t = threadIdx.x;
  for (int idx = t; idx < 900; idx += 256) si[idx] = 0.f;
  for (int idx = t; idx < 288; idx += 256) sw[idx] = w[idx];
  if (t < 32) sb[t] = bias[t];
  __syncthreads();
  for (int idx = t; idx < 784; idx += 256) {
    int y = idx / 28, xx = idx - y*28;
    si[(y+1)*30 + xx + 1] = x[n*784 + idx];
  }
  __syncthreads();
  for (int item = t; item < 6272; item += 256) {
    int c = item / 196, rem = item - c*196;
    int py = rem / 14, px = rem - py*14;
    float pt[4][4];
#pragma unroll
    for (int r = 0; r < 4; ++r)
#pragma unroll
      for (int q = 0; q < 4; ++q)
        pt[r][q] = si[(2*py + r)*30 + 2*px + q];
    const float* wc = &sw[c*9];
    float w0=wc[0], w1=wc[1], w2=wc[2], w3=wc[3], w4=wc[4], w5=wc[5], w6=wc[6], w7=wc[7], w8=wc[8];
    float bb = sb[c];
    float best = 0.f;  // maxpool(relu(v)) == max(0, max v)
#pragma unroll
    for (int a = 0; a < 2; ++a)
#pragma unroll
      for (int b2 = 0; b2 < 2; ++b2) {
        float v = bb
          + w0*pt[a+0][b2+0] + w1*pt[a+0][b2+1] + w2*pt[a+0][b2+2]
          + w3*pt[a+1][b2+0] + w4*pt[a+1][b2+1] + w5*pt[a+1][b2+2]
          + w6*pt[a+2][b2+0] + w7*pt[a+2][b2+1] + w8*pt[a+2][b2+2];
        best = fmaxf(best, v);
      }
    h1[n*6272 + item] = best;
  }
}

// ---------------- k2: conv2 (32->64, 3x3 SAME) + ReLU + maxpool2 ----------------
// One block per image. 256 threads = 16 cgroups(4 ch) x 16 tiles(2x2 pooled px).
// Register tile: 4 c_out x 4x4 conv positions -> 64 accs, 6x6 input patch.
__global__ __launch_bounds__(256) void k2_conv2(const float* __restrict__ h1,
    const float* __restrict__ w, const float* __restrict__ bias,
    float* __restrict__ h2) {
  __shared__ float sin_[32*18*18];   // padded 14x14 -> 18x18 (offset +1), zero borders
  __shared__ float sw_[64*32*9];
  __shared__ float sb_[64];
  const int n = blockIdx.x, t = threadIdx.x;
  for (int idx = t; idx < 32*324; idx += 256) sin_[idx] = 0.f;
  for (int idx = t; idx < 18432; idx += 256) sw_[idx] = w[idx];
  if (t < 64) sb_[t] = bias[t];
  __syncthreads();
  for (int idx = t; idx < 6272; idx += 256) {
    int c = idx / 196, rem = idx - c*196, y = rem / 14, xx = rem - y*14;
    sin_[c*324 + (y+1)*18 + xx + 1] = h1[n*6272 + idx];
  }
  __syncthreads();
  const int cg = t >> 4;              // 0..15 -> c_out base cg*4
  const int tile = t & 15;
  const int ty = tile >> 2, tx = tile & 3;   // 2x2 pooled-tile origin (2ty,2tx)
  float acc[4][4][4];
#pragma unroll
  for (int c = 0; c < 4; ++c) {
    float bb = sb_[cg*4 + c];
#pragma unroll
    for (int r = 0; r < 4; ++r)
#pragma unroll
      for (int q = 0; q < 4; ++q) acc[c][r][q] = bb;
  }
  for (int cin = 0; cin < 32; ++cin) {
    float patch[6][6];
    const float* ib = &sin_[cin*324 + (4*ty)*18 + 4*tx];
#pragma unroll
    for (int r = 0; r < 6; ++r)
#pragma unroll
      for (int q = 0; q < 6; ++q) patch[r][q] = ib[r*18 + q];
#pragma unroll
    for (int dy = 0; dy < 3; ++dy)
#pragma unroll
      for (int dx = 0; dx < 3; ++dx) {
        float wv0 = sw_[(cg*4+0)*288 + cin*9 + dy*3 + dx];
        float wv1 = sw_[(cg*4+1)*288 + cin*9 + dy*3 + dx];
        float wv2 = sw_[(cg*4+2)*288 + cin*9 + dy*3 + dx];
        float wv3 = sw_[(cg*4+3)*288 + cin*9 + dy*3 + dx];
#pragma unroll
        for (int r = 0; r < 4; ++r)
#pragma unroll
          for (int q = 0; q < 4; ++q) {
            float pv = patch[r+dy][q+dx];
            acc[0][r][q] += wv0 * pv;
            acc[1][r][q] += wv1 * pv;
            acc[2][r][q] += wv2 * pv;
            acc[3][r][q] += wv3 * pv;
          }
      }
  }
#pragma unroll
  for (int c = 0; c < 4; ++c) {
    int co = cg*4 + c;
#pragma unroll
    for (int t2 = 0; t2 < 2; ++t2) {
      int py = 2*ty + t2;
      if (py > 6) continue;
#pragma unroll
      for (int t3 = 0; t3 < 2; ++t3) {
        int px = 2*tx + t3;
        if (px > 6) continue;
        float m = fmaxf(fmaxf(acc[c][2*t2][2*t3], acc[c][2*t2][2*t3+1]),
                        fmaxf(acc[c][2*t2+1][2*t3], acc[c][2*t2+1][2*t3+1]));
        h2[n*3136 + co*49 + py*7 + px] = fmaxf(m, 0.f);
      }
    }
  }
}

// ---------------- k3: FC 3136->64 + ReLU (4 images per block) ----------------
__global__ __launch_bounds__(256) void k3_fc(const float* __restrict__ h2,
    const float* __restrict__ fw, const float* __restrict__ fb,
    float* __restrict__ feat) {
  __shared__ __align__(16) float sh[4*3136];
  __shared__ float sred[4][4][64];
  const int blk = blockIdx.x, t = threadIdx.x;
  const int e = t & 63, part = t >> 6;
  for (int idx = t; idx < 4*3136; idx += 256) sh[idx] = h2[blk*4*3136 + idx];
  __syncthreads();
  float a0=0.f, a1=0.f, a2=0.f, a3=0.f;
  const float4* w4 = (const float4*)(fw + e*3136 + part*784);
  const float4* s0 = (const float4*)(sh + part*784);
  const float4* s1 = (const float4*)(sh + 3136 + part*784);
  const float4* s2 = (const float4*)(sh + 6272 + part*784);
  const float4* s3 = (const float4*)(sh + 9408 + part*784);
  for (int q = 0; q < 196; ++q) {
    float4 wv = w4[q];
    float4 v0 = s0[q], v1 = s1[q], v2 = s2[q], v3 = s3[q];
    a0 += wv.x*v0.x + wv.y*v0.y + wv.z*v0.z + wv.w*v0.w;
    a1 += wv.x*v1.x + wv.y*v1.y + wv.z*v1.z + wv.w*v1.w;
    a2 += wv.x*v2.x + wv.y*v2.y + wv.z*v2.z + wv.w*v2.w;
    a3 += wv.x*v3.x + wv.y*v3.y + wv.z*v3.z + wv.w*v3.w;
  }
  sred[part][0][e] = a0; sred[part][1][e] = a1;
  sred[part][2][e] = a2; sred[part][3][e] = a3;
  __syncthreads();
  int img = t >> 6, ee = t & 63;
  float v = sred[0][img][ee] + sred[1][img][ee] + sred[2][img][ee] + sred[3][img][ee] + fb[ee];
  feat[(blk*4 + img)*64 + ee] = fmaxf(v, 0.f);
}

// ---------------- k4a: transpose eq_w (d,e,m) -> Wt[m][d][e] ----------------
__global__ __launch_bounds__(256) void k4_wt(const float* __restrict__ eqw,
                                             float* __restrict__ Wt) {
  const int m = blockIdx.x, t = threadIdx.x;
  for (int idx = t; idx < 4096; idx += 256) {
    int d = idx >> 6, e = idx & 63;
    Wt[m*4096 + idx] = eqw[d*512 + e*8 + m];
  }
}

// ---------------- k4b: s[b,d], t7c[b,e] = s^3 W7 + eq_b, zero x8 ----------------
__global__ __launch_bounds__(64) void k4_prep(const float* __restrict__ feat,
    const float* __restrict__ Wt, const float* __restrict__ eqb,
    float* __restrict__ s, float* __restrict__ t7c, float* __restrict__ x8) {
  __shared__ float ss[64];
  const int b = blockIdx.x, t = threadIdx.x;
  float a = 0.f;
  for (int i = 0; i < 32; ++i) a += feat[(b*32 + i)*64 + t];
  a *= (1.f/32.f);
  s[b*64 + t] = a;
  ss[t] = a;
  __syncthreads();
  const float* W7 = Wt + 7*4096;
  float t7 = 0.f;
  for (int d = 0; d < 64; ++d) {
    float sv = ss[d];
    t7 += sv*sv*sv * W7[d*64 + t];
  }
  t7c[b*64 + t] = t7 + eqb[t];
  x8[b*64 + t] = 0.f;
}

// ---------------- k5: fused equivariant layer + relu + mean (block = (i,b)) ----------------
// x6[e,j,k] = sum_d Pt[jk,d]*Qp[d,e] + KC[k,e] + JC[j,e] + C0[e];  accumulate relu into x8[b,e]
__global__ __launch_bounds__(256) void k5_main(const float* __restrict__ feat,
    const float* __restrict__ s_, const float* __restrict__ Wt,
    const float* __restrict__ t7c, float* __restrict__ x8) {
  // shared layout (floats): F:0(2048) SV:2048(64) QP:2112(4096) KC:6208(2048)
  //                         JC:8256(2048) C0:10304(64) C0P:10368(256) SCR:10624(8448)
  __shared__ __align__(16) float SH[19072];
  float* Fm  = SH;
  float* SV  = SH + 2048;
  float* QP  = SH + 2112;
  float* KC  = SH + 6208;
  float* JC  = SH + 8256;
  float* C0  = SH + 10304;
  float* C0P = SH + 10368;
  float* SCR = SH + 10624;
  float* G2 = SCR;             // phase 1
  float* G3 = SCR + 4096;      // phase 1
  float* PT = SCR;             // phase 2: [128 jk][stride 66]
  float* RED = SCR;            // phase 3

  const int i = blockIdx.x, b = blockIdx.y, t = threadIdx.x;
  const float* W0g = Wt;
  const float* W1g = Wt + 4096;
  const float* W2g = Wt + 8192;
  const float* W3g = Wt + 12288;
  const float* W4g = Wt + 16384;
  const float* W5g = Wt + 20480;
  const float* W6g = Wt + 24576;

  for (int idx = t; idx < 2048; idx += 256) Fm[idx] = feat[b*2048 + idx];
  if (t < 64) SV[t] = s_[b*64 + t];
  __syncthreads();

  // Qp = f_i*W0 + s*W1 ; G2 = s*(f_i*W2 + s*W4) ; G3 = s*(f_i*W3 + s*W5)
  for (int idx = t; idx < 4096; idx += 256) {
    int d = idx >> 6;
    float fi = Fm[i*64 + d], sd = SV[d];
    QP[idx] = fi * W0g[idx] + sd * W1g[idx];
    G2[idx] = sd * (fi * W2g[idx] + sd * W4g[idx]);
    G3[idx] = sd * (fi * W3g[idx] + sd * W5g[idx]);
  }
  __syncthreads();

  // KC[k,e] = F @ G2 ; JC[j,e] = F @ G3  (32x64, K=64)
  for (int idx = t; idx < 2048; idx += 256) {
    int k = idx >> 6, e = idx & 63;
    float a2 = 0.f, a3 = 0.f;
    for (int d = 0; d < 64; d += 4) {
      float4 fk = *(const float4*)&Fm[k*64 + d];
      a2 += fk.x*G2[d*64+e] + fk.y*G2[(d+1)*64+e] + fk.z*G2[(d+2)*64+e] + fk.w*G2[(d+3)*64+e];
      a3 += fk.x*G3[d*64+e] + fk.y*G3[(d+1)*64+e] + fk.z*G3[(d+2)*64+e] + fk.w*G3[(d+3)*64+e];
    }
    KC[idx] = a2; JC[idx] = a3;
  }
  // c0 partials: sum_d s^2 f_i W6 (4-way split over d)
  {
    int e = t & 63, dq = t >> 6;
    float a = 0.f;
    for (int dd = 0; dd < 16; ++dd) {
      int d = dq*16 + dd;
      float sd = SV[d];
      a += sd*sd*Fm[i*64 + d]*W6g[d*64 + e];
    }
    C0P[t] = a;
  }
  __syncthreads();
  if (t < 64) C0[t] = C0P[t] + C0P[64+t] + C0P[128+t] + C0P[192+t] + t7c[b*64 + t];

  const int e8 = (t & 7) * 8;   // 8 e per thread
  const int jg = t >> 3;        // 32 groups x 4 jk
  float sum[8];
#pragma unroll
  for (int c = 0; c < 8; ++c) sum[c] = 0.f;

  for (int tile = 0; tile < 8; ++tile) {
    __syncthreads();   // protect SCR transition (G2/G3 or previous PT readers done)
    for (int idx = t; idx < 8192; idx += 256) {
      int jkl = idx >> 6, d = idx & 63;
      int jkg = tile*128 + jkl;
      PT[jkl*66 + d] = Fm[(jkg >> 5)*64 + d] * Fm[(jkg & 31)*64 + d];
    }
    __syncthreads();
    float acc[4][8];
#pragma unroll
    for (int u = 0; u < 4; ++u)
#pragma unroll
      for (int c = 0; c < 8; ++c) acc[u][c] = 0.f;
    for (int d = 0; d < 64; d += 2) {
      float4 qa0 = *(const float4*)&QP[d*64 + e8];
      float4 qb0 = *(const float4*)&QP[d*64 + e8 + 4];
      float4 qa1 = *(const float4*)&QP[d*64 + 64 + e8];
      float4 qb1 = *(const float4*)&QP[d*64 + 64 + e8 + 4];
#pragma unroll
      for (int u = 0; u < 4; ++u) {
        float2 p = *(const float2*)&PT[(jg*4 + u)*66 + d];
        acc[u][0] += p.x*qa0.x + p.y*qa1.x;
        acc[u][1] += p.x*qa0.y + p.y*qa1.y;
        acc[u][2] += p.x*qa0.z + p.y*qa1.z;
        acc[u][3] += p.x*qa0.w + p.y*qa1.w;
        acc[u][4] += p.x*qb0.x + p.y*qb1.x;
        acc[u][5] += p.x*qb0.y + p.y*qb1.y;
        acc[u][6] += p.x*qb0.z + p.y*qb1.z;
        acc[u][7] += p.x*qb0.w + p.y*qb1.w;
      }
    }
    int j = tile*4 + (jg >> 3);
    float4 jcA = *(const float4*)&JC[j*64 + e8];
    float4 jcB = *(const float4*)&JC[j*64 + e8 + 4];
    float4 c0A = *(const float4*)&C0[e8];
    float4 c0B = *(const float4*)&C0[e8 + 4];
#pragma unroll
    for (int u = 0; u < 4; ++u) {
      int k = (jg & 7)*4 + u;
      float4 kcA = *(const float4*)&KC[k*64 + e8];
      float4 kcB = *(const float4*)&KC[k*64 + e8 + 4];
      sum[0] += fmaxf(acc[u][0] + jcA.x + kcA.x + c0A.x, 0.f);
      sum[1] += fmaxf(acc[u][1] + jcA.y + kcA.y + c0A.y, 0.f);
      sum[2] += fmaxf(acc[u][2] + jcA.z + kcA.z + c0A.z, 0.f);
      sum[3] += fmaxf(acc[u][3] + jcA.w + kcA.w + c0A.w, 0.f);
      sum[4] += fmaxf(acc[u][4] + jcB.x + kcB.x + c0B.x, 0.f);
      sum[5] += fmaxf(acc[u][5] + jcB.y + kcB.y + c0B.y, 0.f);
      sum[6] += fmaxf(acc[u][6] + jcB.z + kcB.z + c0B.z, 0.f);
      sum[7] += fmaxf(acc[u][7] + jcB.w + kcB.w + c0B.w, 0.f);
    }
  }
  __syncthreads();
#pragma unroll
  for (int c = 0; c < 8; ++c) RED[jg*64 + e8 + c] = sum[c];
  __syncthreads();
  if (t < 64) {
    float tot = 0.f;
    for (int g2 = 0; g2 < 32; ++g2) tot += RED[g2*64 + t];
    atomicAdd(&x8[b*64 + t], tot);
  }
}

// ---------------- k6: x9 = relu(x8/K^3); out = x9 @ out_w.T + out_b ----------------
__global__ __launch_bounds__(64) void k6_out(const float* __restrict__ x8,
    const float* __restrict__ ow, const float* __restrict__ ob,
    float* __restrict__ out) {
  const int bb = blockIdx.x, t = threadIdx.x;
  float v = fmaxf(x8[bb*64 + t] * (1.f/32768.f), 0.f) * ow[t];
#pragma unroll
  for (int off = 32; off > 0; off >>= 1) v += __shfl_down(v, off, 64);
  if (t == 0) out[bb] = v + ob[0];
}

extern "C" void kernel_launch(void* const* d_in, const int* in_sizes, int n_in,
                              void* d_out, int out_size, void* d_ws, size_t ws_size,
                              hipStream_t stream) {
  const float* x   = (const float*)d_in[0];
  const float* c1w = (const float*)d_in[1];
  const float* c1b = (const float*)d_in[2];
  const float* c2w = (const float*)d_in[3];
  const float* c2b = (const float*)d_in[4];
  const float* fcw = (const float*)d_in[5];
  const float* fcb = (const float*)d_in[6];
  const float* eqw = (const float*)d_in[7];
  const float* eqb = (const float*)d_in[8];
  const float* ow  = (const float*)d_in[9];
  const float* ob  = (const float*)d_in[10];
  float* out = (float*)d_out;

  float* ws   = (float*)d_ws;
  float* h1   = ws;                      // 512*6272
  float* h2   = h1 + 512*6272;           // 512*3136
  float* feat = h2 + 512*3136;           // 512*64
  float* s    = feat + 512*64;           // 16*64
  float* t7c  = s + 1024;                // 16*64
  float* x8   = t7c + 1024;              // 16*64
  float* Wt   = x8 + 1024;               // 8*64*64

  hipLaunchKernelGGL(k1_conv1, dim3(512), dim3(256), 0, stream, x, c1w, c1b, h1);
  hipLaunchKernelGGL(k2_conv2, dim3(512), dim3(256), 0, stream, h1, c2w, c2b, h2);
  hipLaunchKernelGGL(k3_fc,    dim3(128), dim3(256), 0, stream, h2, fcw, fcb, feat);
  hipLaunchKernelGGL(k4_wt,    dim3(8),   dim3(256), 0, stream, eqw, Wt);
  hipLaunchKernelGGL(k4_prep,  dim3(16),  dim3(64),  0, stream, feat, Wt, eqb, s, t7c, x8);
  hipLaunchKernelGGL(k5_main,  dim3(32, 16), dim3(256), 0, stream, feat, s, Wt, t7c, x8);
  hipLaunchKernelGGL(k6_out,   dim3(16),  dim3(64),  0, stream, x8, ow, ob, out);
}

// Round 2
// 221.728 us; speedup vs baseline: 1.3165x; 1.3165x over previous
//
#include <hip/hip_runtime.h>

// B=16, K=32, H=W=28, HID=OUT=64, NOPS=8
// ws layout (floats): h1[512*6272] h2[512*3136] feat[512*64] s[16*64] t7c[16*64]
//                     x8[16*64] Wt[8*64*64]   (Wt layout: [m][e][d])

typedef __attribute__((ext_vector_type(8))) short short8;
typedef __attribute__((ext_vector_type(4))) float f32x4;

__device__ __forceinline__ f32x4 mfma_bf16(short8 a, short8 b, f32x4 c) {
  return __builtin_amdgcn_mfma_f32_16x16x32_bf16(a, b, c, 0, 0, 0);
}

// float -> bf16 bits, round-to-nearest-even (finite inputs only)
__device__ __forceinline__ unsigned short f2bs(float f) {
  unsigned int u = __float_as_uint(f);
  unsigned int r = u + 0x7fffu + ((u >> 16) & 1u);
  return (unsigned short)(r >> 16);
}
__device__ __forceinline__ unsigned int pk2(float x, float y) {
  return (unsigned int)f2bs(x) | ((unsigned int)f2bs(y) << 16);
}
// store float4 as 4 bf16 at p (p 4-short aligned)
__device__ __forceinline__ void stb4(short* p, float4 v) {
  *(unsigned int*)(p)     = pk2(v.x, v.y);
  *(unsigned int*)(p + 2) = pk2(v.z, v.w);
}

// ---------------- k1: conv1 (1->32, 3x3 SAME) + ReLU + maxpool2 ----------------
__global__ __launch_bounds__(256) void k1_conv1(const float* __restrict__ x,
    const float* __restrict__ w, const float* __restrict__ bias,
    float* __restrict__ h1) {
  __shared__ float si[30*30];
  __shared__ float sw[32*9];
  __shared__ float sb[32];
  const int n = blockIdx.x, t = threadIdx.x;
  for (int idx = t; idx < 900; idx += 256) si[idx] = 0.f;
  for (int idx = t; idx < 288; idx += 256) sw[idx] = w[idx];
  if (t < 32) sb[t] = bias[t];
  __syncthreads();
  for (int idx = t; idx < 784; idx += 256) {
    int y = idx / 28, xx = idx - y*28;
    si[(y+1)*30 + xx + 1] = x[n*784 + idx];
  }
  __syncthreads();
  for (int item = t; item < 6272; item += 256) {
    int c = item / 196, rem = item - c*196;
    int py = rem / 14, px = rem - py*14;
    float pt[4][4];
#pragma unroll
    for (int r = 0; r < 4; ++r)
#pragma unroll
      for (int q = 0; q < 4; ++q)
        pt[r][q] = si[(2*py + r)*30 + 2*px + q];
    const float* wc = &sw[c*9];
    float w0=wc[0], w1=wc[1], w2=wc[2], w3=wc[3], w4=wc[4], w5=wc[5], w6=wc[6], w7=wc[7], w8=wc[8];
    float bb = sb[c];
    float best = 0.f;
#pragma unroll
    for (int a = 0; a < 2; ++a)
#pragma unroll
      for (int b2 = 0; b2 < 2; ++b2) {
        float v = bb
          + w0*pt[a+0][b2+0] + w1*pt[a+0][b2+1] + w2*pt[a+0][b2+2]
          + w3*pt[a+1][b2+0] + w4*pt[a+1][b2+1] + w5*pt[a+1][b2+2]
          + w6*pt[a+2][b2+0] + w7*pt[a+2][b2+1] + w8*pt[a+2][b2+2];
        best = fmaxf(best, v);
      }
    h1[n*6272 + item] = best;
  }
}

// ---------------- k2: conv2 (32->64, 3x3 SAME) + ReLU + maxpool2 ----------------
__global__ __launch_bounds__(256) void k2_conv2(const float* __restrict__ h1,
    const float* __restrict__ w, const float* __restrict__ bias,
    float* __restrict__ h2) {
  __shared__ float sin_[32*18*18];
  __shared__ float sw_[64*32*9];
  __shared__ float sb_[64];
  const int n = blockIdx.x, t = threadIdx.x;
  for (int idx = t; idx < 32*324; idx += 256) sin_[idx] = 0.f;
  for (int idx = t; idx < 18432; idx += 256) sw_[idx] = w[idx];
  if (t < 64) sb_[t] = bias[t];
  __syncthreads();
  for (int idx = t; idx < 6272; idx += 256) {
    int c = idx / 196, rem = idx - c*196, y = rem / 14, xx = rem - y*14;
    sin_[c*324 + (y+1)*18 + xx + 1] = h1[n*6272 + idx];
  }
  __syncthreads();
  const int cg = t >> 4;
  const int tile = t & 15;
  const int ty = tile >> 2, tx = tile & 3;
  float acc[4][4][4];
#pragma unroll
  for (int c = 0; c < 4; ++c) {
    float bb = sb_[cg*4 + c];
#pragma unroll
    for (int r = 0; r < 4; ++r)
#pragma unroll
      for (int q = 0; q < 4; ++q) acc[c][r][q] = bb;
  }
  for (int cin = 0; cin < 32; ++cin) {
    float patch[6][6];
    const float* ib = &sin_[cin*324 + (4*ty)*18 + 4*tx];
#pragma unroll
    for (int r = 0; r < 6; ++r)
#pragma unroll
      for (int q = 0; q < 6; ++q) patch[r][q] = ib[r*18 + q];
#pragma unroll
    for (int dy = 0; dy < 3; ++dy)
#pragma unroll
      for (int dx = 0; dx < 3; ++dx) {
        float wv0 = sw_[(cg*4+0)*288 + cin*9 + dy*3 + dx];
        float wv1 = sw_[(cg*4+1)*288 + cin*9 + dy*3 + dx];
        float wv2 = sw_[(cg*4+2)*288 + cin*9 + dy*3 + dx];
        float wv3 = sw_[(cg*4+3)*288 + cin*9 + dy*3 + dx];
#pragma unroll
        for (int r = 0; r < 4; ++r)
#pragma unroll
          for (int q = 0; q < 4; ++q) {
            float pv = patch[r+dy][q+dx];
            acc[0][r][q] += wv0 * pv;
            acc[1][r][q] += wv1 * pv;
            acc[2][r][q] += wv2 * pv;
            acc[3][r][q] += wv3 * pv;
          }
      }
  }
#pragma unroll
  for (int c = 0; c < 4; ++c) {
    int co = cg*4 + c;
#pragma unroll
    for (int t2 = 0; t2 < 2; ++t2) {
      int py = 2*ty + t2;
      if (py > 6) continue;
#pragma unroll
      for (int t3 = 0; t3 < 2; ++t3) {
        int px = 2*tx + t3;
        if (px > 6) continue;
        float m = fmaxf(fmaxf(acc[c][2*t2][2*t3], acc[c][2*t2][2*t3+1]),
                        fmaxf(acc[c][2*t2+1][2*t3], acc[c][2*t2+1][2*t3+1]));
        h2[n*3136 + co*49 + py*7 + px] = fmaxf(m, 0.f);
      }
    }
  }
}

// ---------------- k3: FC 3136->64 + ReLU (4 images per block) ----------------
__global__ __launch_bounds__(256) void k3_fc(const float* __restrict__ h2,
    const float* __restrict__ fw, const float* __restrict__ fb,
    float* __restrict__ feat) {
  __shared__ __align__(16) float sh[4*3136];
  __shared__ float sred[4][4][64];
  const int blk = blockIdx.x, t = threadIdx.x;
  const int e = t & 63, part = t >> 6;
  for (int idx = t; idx < 4*3136; idx += 256) sh[idx] = h2[blk*4*3136 + idx];
  __syncthreads();
  float a0=0.f, a1=0.f, a2=0.f, a3=0.f;
  const float4* w4 = (const float4*)(fw + e*3136 + part*784);
  const float4* s0 = (const float4*)(sh + part*784);
  const float4* s1 = (const float4*)(sh + 3136 + part*784);
  const float4* s2 = (const float4*)(sh + 6272 + part*784);
  const float4* s3 = (const float4*)(sh + 9408 + part*784);
  for (int q = 0; q < 196; ++q) {
    float4 wv = w4[q];
    float4 v0 = s0[q], v1 = s1[q], v2 = s2[q], v3 = s3[q];
    a0 += wv.x*v0.x + wv.y*v0.y + wv.z*v0.z + wv.w*v0.w;
    a1 += wv.x*v1.x + wv.y*v1.y + wv.z*v1.z + wv.w*v1.w;
    a2 += wv.x*v2.x + wv.y*v2.y + wv.z*v2.z + wv.w*v2.w;
    a3 += wv.x*v3.x + wv.y*v3.y + wv.z*v3.z + wv.w*v3.w;
  }
  sred[part][0][e] = a0; sred[part][1][e] = a1;
  sred[part][2][e] = a2; sred[part][3][e] = a3;
  __syncthreads();
  int img = t >> 6, ee = t & 63;
  float v = sred[0][img][ee] + sred[1][img][ee] + sred[2][img][ee] + sred[3][img][ee] + fb[ee];
  feat[(blk*4 + img)*64 + ee] = fmaxf(v, 0.f);
}

// ---------------- k4a: transpose eq_w (d,e,m) -> Wt[m][e][d] ----------------
__global__ __launch_bounds__(256) void k4_wt(const float* __restrict__ eqw,
                                             float* __restrict__ Wt) {
  const int m = blockIdx.x, t = threadIdx.x;
  for (int idx = t; idx < 4096; idx += 256) {
    int e = idx >> 6, d = idx & 63;
    Wt[m*4096 + idx] = eqw[d*512 + e*8 + m];
  }
}

// ---------------- k4b: s[b,d], t7c[b,e] = s^3 W7 + eq_b, zero x8 ----------------
__global__ __launch_bounds__(64) void k4_prep(const float* __restrict__ feat,
    const float* __restrict__ Wt, const float* __restrict__ eqb,
    float* __restrict__ s, float* __restrict__ t7c, float* __restrict__ x8) {
  __shared__ float ss[64];
  const int b = blockIdx.x, t = threadIdx.x;
  float a = 0.f;
  for (int i = 0; i < 32; ++i) a += feat[(b*32 + i)*64 + t];
  a *= (1.f/32.f);
  s[b*64 + t] = a;
  ss[t] = a;
  __syncthreads();
  const float* W7 = Wt + 7*4096 + t*64;   // [m=7][e=t][d]
  float t7 = 0.f;
  for (int d = 0; d < 64; ++d) {
    float sv = ss[d];
    t7 += sv*sv*sv * W7[d];
  }
  t7c[b*64 + t] = t7 + eqb[t];
  x8[b*64 + t] = 0.f;
}

// ---------------- k5: fused equivariant layer via bf16 MFMA ----------------
// Per block (i,b): D[jk(1024) x e(64)] = PT @ QP; x6 = D + JC[j] + KC[k] + C0;
// accumulate mean(relu(x6)) into x8[b,e].
__global__ __launch_bounds__(256, 2) void k5_mfma(const float* __restrict__ feat,
    const float* __restrict__ s_, const float* __restrict__ Wt,
    const float* __restrict__ t7c, float* __restrict__ x8) {
  __shared__ __align__(16) float Fm[32*68];     // feat fp32, stride 68 (bank-pad)
  __shared__ __align__(16) float FI[64];        // feat[b,i,:]
  __shared__ __align__(16) float SV[64];        // s[b,:]
  __shared__ __align__(16) float C0[64];
  __shared__ float C0P[128];
  __shared__ float KCf[32*68];
  __shared__ float JCf[32*68];
  __shared__ float RED[256];
  __shared__ __align__(16) short Fb[32*72];     // feat bf16, stride 72
  __shared__ __align__(16) short QPb[64*72];    // [e][d] bf16
  __shared__ __align__(16) short G2b[64*72];    // [e][d] bf16
  __shared__ __align__(16) short G3b[64*72];    // [e][d] bf16

  const int i = blockIdx.x, b = blockIdx.y, t = threadIdx.x;
  const int w = t >> 6, l = t & 63, quad = l >> 4, col = l & 15;

  // ---- P0a: stage feat (fp32 + bf16), FI, SV ----
  for (int idx = t; idx < 2048; idx += 256) {
    int r = idx >> 6, d = idx & 63;
    float v = feat[b*2048 + idx];
    Fm[r*68 + d] = v;
    Fb[r*72 + d] = (short)f2bs(v);
  }
  if (t < 64) { FI[t] = feat[b*2048 + i*64 + t]; SV[t] = s_[b*64 + t]; }
  __syncthreads();

  // ---- P0b: build QPb/G2b/G3b ([e][d] bf16) and C0 partials ----
  {
    const int e = t >> 2, dbase = (t & 3) * 16;
    const float* W0 = Wt + 0*4096 + e*64;
    const float* W1 = Wt + 1*4096 + e*64;
    const float* W2 = Wt + 2*4096 + e*64;
    const float* W3 = Wt + 3*4096 + e*64;
    const float* W4 = Wt + 4*4096 + e*64;
    const float* W5 = Wt + 5*4096 + e*64;
#pragma unroll
    for (int q = 0; q < 4; ++q) {
      int off = dbase + q*4;
      float4 fi4 = *(const float4*)&FI[off];
      float4 sv4 = *(const float4*)&SV[off];
      float4 w0 = *(const float4*)&W0[off];
      float4 w1 = *(const float4*)&W1[off];
      float4 w2 = *(const float4*)&W2[off];
      float4 w3 = *(const float4*)&W3[off];
      float4 w4 = *(const float4*)&W4[off];
      float4 w5 = *(const float4*)&W5[off];
      float4 qp = fi4*w0 + sv4*w1;
      float4 g2 = sv4*(fi4*w2 + sv4*w4);
      float4 g3 = sv4*(fi4*w3 + sv4*w5);
      stb4(&QPb[e*72 + off], qp);
      stb4(&G2b[e*72 + off], g2);
      stb4(&G3b[e*72 + off], g3);
    }
  }
  if (t < 128) {
    int e = t & 63, dh = t >> 6;
    const float* W6 = Wt + 6*4096 + e*64 + dh*32;
    const float* fip = FI + dh*32;
    const float* svp = SV + dh*32;
    float a = 0.f;
#pragma unroll
    for (int dd = 0; dd < 32; ++dd) {
      float sd = svp[dd];
      a += sd*sd*fip[dd]*W6[dd];
    }
    C0P[dh*64 + e] = a;
  }
  __syncthreads();

  // ---- P2: KC = F@G2 (wave0), JC = F@G3 (wave1) via MFMA; C0 combine (wave2) ----
  if (w < 2) {
    const short* G = w ? G3b : G2b;
    float* DST = w ? JCf : KCf;
    short8 Bf[4][2];
#pragma unroll
    for (int n = 0; n < 4; ++n)
#pragma unroll
      for (int s2 = 0; s2 < 2; ++s2)
        Bf[n][s2] = *(const short8*)&G[(n*16 + col)*72 + s2*32 + quad*8];
#pragma unroll
    for (int m = 0; m < 2; ++m) {
      short8 A0 = *(const short8*)&Fb[(m*16 + col)*72 + quad*8];
      short8 A1 = *(const short8*)&Fb[(m*16 + col)*72 + 32 + quad*8];
#pragma unroll
      for (int n = 0; n < 4; ++n) {
        f32x4 z = {0.f, 0.f, 0.f, 0.f};
        f32x4 ac = mfma_bf16(A1, Bf[n][1], mfma_bf16(A0, Bf[n][0], z));
#pragma unroll
        for (int r = 0; r < 4; ++r)
          DST[(m*16 + quad*4 + r)*68 + n*16 + col] = ac[r];
      }
    }
  } else if (w == 2) {
    C0[l] = C0P[l] + C0P[64 + l] + t7c[b*64 + l];
  }
  __syncthreads();

  // ---- P3: main GEMM. Wave w handles m-tiles w*16..w*16+15 (rows = jk). ----
  // m-tile mt: rows mt*16+m, j = mt>>1 (const per tile), k = (mt&1)*16 + m.
  float c0v[4];
#pragma unroll
  for (int n = 0; n < 4; ++n) c0v[n] = C0[n*16 + col];
  float jcq[8][4];
#pragma unroll
  for (int jj = 0; jj < 8; ++jj)
#pragma unroll
    for (int n = 0; n < 4; ++n)
      jcq[jj][n] = JCf[(w*8 + jj)*68 + n*16 + col] + c0v[n];
  float kcv[2][4][4];
#pragma unroll
  for (int kb2 = 0; kb2 < 2; ++kb2)
#pragma unroll
    for (int r = 0; r < 4; ++r)
#pragma unroll
      for (int n = 0; n < 4; ++n)
        kcv[kb2][r][n] = KCf[(kb2*16 + quad*4 + r)*68 + n*16 + col];
  short8 Bq[4][2];
#pragma unroll
  for (int n = 0; n < 4; ++n)
#pragma unroll
    for (int s2 = 0; s2 < 2; ++s2)
      Bq[n][s2] = *(const short8*)&QPb[(n*16 + col)*72 + s2*32 + quad*8];

  float sum[4] = {0.f, 0.f, 0.f, 0.f};
  union SU { short8 v; unsigned int u[4]; };

#pragma unroll
  for (int mi = 0; mi < 16; ++mi) {
    const int jj = mi >> 1, kb2 = mi & 1;
    const float* fj = &Fm[(w*8 + jj)*68 + quad*8];
    const float* fk = &Fm[(kb2*16 + col)*68 + quad*8];
    float4 ja0 = *(const float4*)(fj);
    float4 ja1 = *(const float4*)(fj + 4);
    float4 jb0 = *(const float4*)(fj + 32);
    float4 jb1 = *(const float4*)(fj + 36);
    float4 ka0 = *(const float4*)(fk);
    float4 ka1 = *(const float4*)(fk + 4);
    float4 kb0 = *(const float4*)(fk + 32);
    float4 kb1 = *(const float4*)(fk + 36);
    SU A0, A1;
    A0.u[0] = pk2(ja0.x*ka0.x, ja0.y*ka0.y);
    A0.u[1] = pk2(ja0.z*ka0.z, ja0.w*ka0.w);
    A0.u[2] = pk2(ja1.x*ka1.x, ja1.y*ka1.y);
    A0.u[3] = pk2(ja1.z*ka1.z, ja1.w*ka1.w);
    A1.u[0] = pk2(jb0.x*kb0.x, jb0.y*kb0.y);
    A1.u[1] = pk2(jb0.z*kb0.z, jb0.w*kb0.w);
    A1.u[2] = pk2(jb1.x*kb1.x, jb1.y*kb1.y);
    A1.u[3] = pk2(jb1.z*kb1.z, jb1.w*kb1.w);
    f32x4 ac[4];
#pragma unroll
    for (int n = 0; n < 4; ++n) {
      f32x4 z = {0.f, 0.f, 0.f, 0.f};
      ac[n] = mfma_bf16(A1.v, Bq[n][1], mfma_bf16(A0.v, Bq[n][0], z));
    }
#pragma unroll
    for (int n = 0; n < 4; ++n)
#pragma unroll
      for (int r = 0; r < 4; ++r) {
        float v = ac[n][r] + kcv[kb2][r][n] + jcq[jj][n];
        sum[n] += fmaxf(v, 0.f);
      }
  }

  // ---- reduce: quad-sum via shfl, then cross-wave via LDS ----
#pragma unroll
  for (int n = 0; n < 4; ++n) {
    float v = sum[n];
    v += __shfl_xor(v, 16, 64);
    v += __shfl_xor(v, 32, 64);
    if (l < 16) RED[w*64 + n*16 + l] = v;
  }
  __syncthreads();
  if (t < 64) {
    float tot = RED[t] + RED[64 + t] + RED[128 + t] + RED[192 + t];
    atomicAdd(&x8[b*64 + t], tot);
  }
}

// ---------------- k6: x9 = relu(x8/K^3); out = x9 @ out_w.T + out_b ----------------
__global__ __launch_bounds__(64) void k6_out(const float* __restrict__ x8,
    const float* __restrict__ ow, const float* __restrict__ ob,
    float* __restrict__ out) {
  const int bb = blockIdx.x, t = threadIdx.x;
  float v = fmaxf(x8[bb*64 + t] * (1.f/32768.f), 0.f) * ow[t];
#pragma unroll
  for (int off = 32; off > 0; off >>= 1) v += __shfl_down(v, off, 64);
  if (t == 0) out[bb] = v + ob[0];
}

extern "C" void kernel_launch(void* const* d_in, const int* in_sizes, int n_in,
                              void* d_out, int out_size, void* d_ws, size_t ws_size,
                              hipStream_t stream) {
  const float* x   = (const float*)d_in[0];
  const float* c1w = (const float*)d_in[1];
  const float* c1b = (const float*)d_in[2];
  const float* c2w = (const float*)d_in[3];
  const float* c2b = (const float*)d_in[4];
  const float* fcw = (const float*)d_in[5];
  const float* fcb = (const float*)d_in[6];
  const float* eqw = (const float*)d_in[7];
  const float* eqb = (const float*)d_in[8];
  const float* ow  = (const float*)d_in[9];
  const float* ob  = (const float*)d_in[10];
  float* out = (float*)d_out;

  float* ws   = (float*)d_ws;
  float* h1   = ws;                      // 512*6272
  float* h2   = h1 + 512*6272;           // 512*3136
  float* feat = h2 + 512*3136;           // 512*64
  float* s    = feat + 512*64;           // 16*64
  float* t7c  = s + 1024;                // 16*64
  float* x8   = t7c + 1024;              // 16*64
  float* Wt   = x8 + 1024;               // 8*64*64

  hipLaunchKernelGGL(k1_conv1, dim3(512), dim3(256), 0, stream, x, c1w, c1b, h1);
  hipLaunchKernelGGL(k2_conv2, dim3(512), dim3(256), 0, stream, h1, c2w, c2b, h2);
  hipLaunchKernelGGL(k3_fc,    dim3(128), dim3(256), 0, stream, h2, fcw, fcb, feat);
  hipLaunchKernelGGL(k4_wt,    dim3(8),   dim3(256), 0, stream, eqw, Wt);
  hipLaunchKernelGGL(k4_prep,  dim3(16),  dim3(64),  0, stream, feat, Wt, eqb, s, t7c, x8);
  hipLaunchKernelGGL(k5_mfma,  dim3(32, 16), dim3(256), 0, stream, feat, s, Wt, t7c, x8);
  hipLaunchKernelGGL(k6_out,   dim3(16),  dim3(64),  0, stream, x8, ow, ob, out);
}

// Round 3
// 167.505 us; speedup vs baseline: 1.7426x; 1.3237x over previous
//
#include <hip/hip_runtime.h>

// B=16, K=32, H=W=28, HID=OUT=64, NOPS=8
// ws layout (floats): h1[512*6272] h2[512*3136] feat[512*64] s[16*64] t7c[16*64]
//                     x8[16*64] Wt[8*64*64]   (Wt layout: [m][e][d])

typedef __attribute__((ext_vector_type(8))) short short8;
typedef __attribute__((ext_vector_type(4))) float f32x4;

__device__ __forceinline__ f32x4 mfma_bf16(short8 a, short8 b, f32x4 c) {
  return __builtin_amdgcn_mfma_f32_16x16x32_bf16(a, b, c, 0, 0, 0);
}

// float -> bf16 bits, round-to-nearest-even (finite inputs only)
__device__ __forceinline__ unsigned short f2bs(float f) {
  unsigned int u = __float_as_uint(f);
  unsigned int r = u + 0x7fffu + ((u >> 16) & 1u);
  return (unsigned short)(r >> 16);
}
__device__ __forceinline__ unsigned int pk2(float x, float y) {
  return (unsigned int)f2bs(x) | ((unsigned int)f2bs(y) << 16);
}
__device__ __forceinline__ void stb4(short* p, float4 v) {
  *(unsigned int*)(p)     = pk2(v.x, v.y);
  *(unsigned int*)(p + 2) = pk2(v.z, v.w);
}

// ---------------- k1: conv1 (1->32, 3x3 SAME) + ReLU + maxpool2 ----------------
__global__ __launch_bounds__(256) void k1_conv1(const float* __restrict__ x,
    const float* __restrict__ w, const float* __restrict__ bias,
    float* __restrict__ h1) {
  __shared__ float si[30*30];
  __shared__ float sw[32*9];
  __shared__ float sb[32];
  const int n = blockIdx.x, t = threadIdx.x;
  for (int idx = t; idx < 900; idx += 256) si[idx] = 0.f;
  for (int idx = t; idx < 288; idx += 256) sw[idx] = w[idx];
  if (t < 32) sb[t] = bias[t];
  __syncthreads();
  for (int idx = t; idx < 784; idx += 256) {
    int y = idx / 28, xx = idx - y*28;
    si[(y+1)*30 + xx + 1] = x[n*784 + idx];
  }
  __syncthreads();
  for (int item = t; item < 6272; item += 256) {
    int c = item / 196, rem = item - c*196;
    int py = rem / 14, px = rem - py*14;
    float pt[4][4];
#pragma unroll
    for (int r = 0; r < 4; ++r)
#pragma unroll
      for (int q = 0; q < 4; ++q)
        pt[r][q] = si[(2*py + r)*30 + 2*px + q];
    const float* wc = &sw[c*9];
    float w0=wc[0], w1=wc[1], w2=wc[2], w3=wc[3], w4=wc[4], w5=wc[5], w6=wc[6], w7=wc[7], w8=wc[8];
    float bb = sb[c];
    float best = 0.f;
#pragma unroll
    for (int a = 0; a < 2; ++a)
#pragma unroll
      for (int b2 = 0; b2 < 2; ++b2) {
        float v = bb
          + w0*pt[a+0][b2+0] + w1*pt[a+0][b2+1] + w2*pt[a+0][b2+2]
          + w3*pt[a+1][b2+0] + w4*pt[a+1][b2+1] + w5*pt[a+1][b2+2]
          + w6*pt[a+2][b2+0] + w7*pt[a+2][b2+1] + w8*pt[a+2][b2+2];
        best = fmaxf(best, v);
      }
    h1[n*6272 + item] = best;
  }
}

// ---------------- k2: conv2 via bf16 MFMA implicit-GEMM ----------------
// One block per image. M = positions (m-tile = one row y, m=x), N = 64 c_out
// (wave w owns c_out w*16..w*16+15), K = (dy,dx)x32cin. Pool is lane-local.
__global__ __launch_bounds__(256, 2) void k2_mfma(const float* __restrict__ h1,
    const float* __restrict__ w, const float* __restrict__ bias,
    float* __restrict__ h2) {
  __shared__ __align__(16) short inT[16*18*40];  // [yy 0..15][xx 0..17][cin stride 40]
  const int n = blockIdx.x, t = threadIdx.x;
  const int wv = t >> 6, l = t & 63, quad = l >> 4, col = l & 15;

  // zero-init (borders must be 0 for SAME padding)
  unsigned int* zp = (unsigned int*)inT;
  for (int idx = t; idx < 16*18*20; idx += 256) zp[idx] = 0u;

  // B fragments: repack global fp32 weights [co][cin][3][3] -> 9 x short8 in regs
  const int c_out = wv*16 + col;
  float w72[72];
  {
    const float4* src = (const float4*)(w + c_out*288 + quad*72);
#pragma unroll
    for (int q = 0; q < 18; ++q) {
      float4 v = src[q];
      w72[q*4+0] = v.x; w72[q*4+1] = v.y; w72[q*4+2] = v.z; w72[q*4+3] = v.w;
    }
  }
  union SU { short8 v; unsigned int u[4]; };
  short8 Bq[9];
#pragma unroll
  for (int dd = 0; dd < 9; ++dd) {
    SU b;
#pragma unroll
    for (int q = 0; q < 4; ++q)
      b.u[q] = pk2(w72[(2*q)*9 + dd], w72[(2*q+1)*9 + dd]);
    Bq[dd] = b.v;
  }
  const float bb = bias[c_out];
  __syncthreads();

  // stage h1 -> inT (bf16, transposed to [pos][cin])
  for (int idx = t; idx < 6272; idx += 256) {
    int c = idx / 196, rem = idx - c*196, y = rem / 14, x = rem - y*14;
    inT[(y+1)*720 + (x+1)*40 + c] = (short)f2bs(h1[n*6272 + idx]);
  }
  __syncthreads();

  // main loop: p = pooled output row; rows y0=2p, y1=2p+1
  for (int p = 0; p < 7; ++p) {
    short8 Ar[4][3];
#pragma unroll
    for (int rr = 0; rr < 4; ++rr)
#pragma unroll
      for (int dx = 0; dx < 3; ++dx)
        Ar[rr][dx] = *(const short8*)&inT[(2*p + rr)*720 + (col + dx)*40 + quad*8];
    f32x4 a0 = {0.f,0.f,0.f,0.f}, a1 = {0.f,0.f,0.f,0.f};
#pragma unroll
    for (int dy = 0; dy < 3; ++dy)
#pragma unroll
      for (int dx = 0; dx < 3; ++dx) {
        a0 = mfma_bf16(Ar[dy][dx],     Bq[dy*3 + dx], a0);
        a1 = mfma_bf16(Ar[dy + 1][dx], Bq[dy*3 + dx], a1);
      }
    // lane-local 2x2 maxpool + relu + store (lane holds x = quad*4+r, c_out = col)
#pragma unroll
    for (int a = 0; a < 2; ++a) {
      int px = quad*2 + a;
      if (px < 7) {
        float m0 = fmaxf(fmaxf(a0[2*a], a0[2*a + 1]), fmaxf(a1[2*a], a1[2*a + 1]));
        h2[n*3136 + c_out*49 + p*7 + px] = fmaxf(m0 + bb, 0.f);
      }
    }
  }
}

// ---------------- k3: FC 3136->64 + ReLU (4 images per block) ----------------
__global__ __launch_bounds__(256) void k3_fc(const float* __restrict__ h2,
    const float* __restrict__ fw, const float* __restrict__ fb,
    float* __restrict__ feat) {
  __shared__ __align__(16) float sh[4*3136];
  __shared__ float sred[4][4][64];
  const int blk = blockIdx.x, t = threadIdx.x;
  const int e = t & 63, part = t >> 6;
  for (int idx = t; idx < 4*3136; idx += 256) sh[idx] = h2[blk*4*3136 + idx];
  __syncthreads();
  float a0=0.f, a1=0.f, a2=0.f, a3=0.f;
  const float4* w4 = (const float4*)(fw + e*3136 + part*784);
  const float4* s0 = (const float4*)(sh + part*784);
  const float4* s1 = (const float4*)(sh + 3136 + part*784);
  const float4* s2 = (const float4*)(sh + 6272 + part*784);
  const float4* s3 = (const float4*)(sh + 9408 + part*784);
  for (int q = 0; q < 196; ++q) {
    float4 wv = w4[q];
    float4 v0 = s0[q], v1 = s1[q], v2 = s2[q], v3 = s3[q];
    a0 += wv.x*v0.x + wv.y*v0.y + wv.z*v0.z + wv.w*v0.w;
    a1 += wv.x*v1.x + wv.y*v1.y + wv.z*v1.z + wv.w*v1.w;
    a2 += wv.x*v2.x + wv.y*v2.y + wv.z*v2.z + wv.w*v2.w;
    a3 += wv.x*v3.x + wv.y*v3.y + wv.z*v3.z + wv.w*v3.w;
  }
  sred[part][0][e] = a0; sred[part][1][e] = a1;
  sred[part][2][e] = a2; sred[part][3][e] = a3;
  __syncthreads();
  int img = t >> 6, ee = t & 63;
  float v = sred[0][img][ee] + sred[1][img][ee] + sred[2][img][ee] + sred[3][img][ee] + fb[ee];
  feat[(blk*4 + img)*64 + ee] = fmaxf(v, 0.f);
}

// ---------------- k4a: transpose eq_w (d,e,m) -> Wt[m][e][d] ----------------
__global__ __launch_bounds__(256) void k4_wt(const float* __restrict__ eqw,
                                             float* __restrict__ Wt) {
  const int m = blockIdx.x, t = threadIdx.x;
  for (int idx = t; idx < 4096; idx += 256) {
    int e = idx >> 6, d = idx & 63;
    Wt[m*4096 + idx] = eqw[d*512 + e*8 + m];
  }
}

// ---------------- k4b: s[b,d], t7c[b,e] = s^3 W7 + eq_b, zero x8 ----------------
__global__ __launch_bounds__(64) void k4_prep(const float* __restrict__ feat,
    const float* __restrict__ Wt, const float* __restrict__ eqb,
    float* __restrict__ s, float* __restrict__ t7c, float* __restrict__ x8) {
  __shared__ float ss[64];
  const int b = blockIdx.x, t = threadIdx.x;
  float a = 0.f;
  for (int i = 0; i < 32; ++i) a += feat[(b*32 + i)*64 + t];
  a *= (1.f/32.f);
  s[b*64 + t] = a;
  ss[t] = a;
  __syncthreads();
  const float* W7 = Wt + 7*4096 + t*64;   // [m=7][e=t][d]
  float t7 = 0.f;
  for (int d = 0; d < 64; ++d) {
    float sv = ss[d];
    t7 += sv*sv*sv * W7[d];
  }
  t7c[b*64 + t] = t7 + eqb[t];
  x8[b*64 + t] = 0.f;
}

// ---------------- k5: fused equivariant layer via bf16 MFMA ----------------
__global__ __launch_bounds__(256, 2) void k5_mfma(const float* __restrict__ feat,
    const float* __restrict__ s_, const float* __restrict__ Wt,
    const float* __restrict__ t7c, float* __restrict__ x8) {
  __shared__ __align__(16) float Fm[32*68];
  __shared__ __align__(16) float FI[64];
  __shared__ __align__(16) float SV[64];
  __shared__ __align__(16) float C0[64];
  __shared__ float C0P[128];
  __shared__ float KCf[32*68];
  __shared__ float JCf[32*68];
  __shared__ float RED[256];
  __shared__ __align__(16) short Fb[32*72];
  __shared__ __align__(16) short QPb[64*72];
  __shared__ __align__(16) short G2b[64*72];
  __shared__ __align__(16) short G3b[64*72];

  const int i = blockIdx.x, b = blockIdx.y, t = threadIdx.x;
  const int w = t >> 6, l = t & 63, quad = l >> 4, col = l & 15;

  for (int idx = t; idx < 2048; idx += 256) {
    int r = idx >> 6, d = idx & 63;
    float v = feat[b*2048 + idx];
    Fm[r*68 + d] = v;
    Fb[r*72 + d] = (short)f2bs(v);
  }
  if (t < 64) { FI[t] = feat[b*2048 + i*64 + t]; SV[t] = s_[b*64 + t]; }
  __syncthreads();

  {
    const int e = t >> 2, dbase = (t & 3) * 16;
    const float* W0 = Wt + 0*4096 + e*64;
    const float* W1 = Wt + 1*4096 + e*64;
    const float* W2 = Wt + 2*4096 + e*64;
    const float* W3 = Wt + 3*4096 + e*64;
    const float* W4 = Wt + 4*4096 + e*64;
    const float* W5 = Wt + 5*4096 + e*64;
#pragma unroll
    for (int q = 0; q < 4; ++q) {
      int off = dbase + q*4;
      float4 fi4 = *(const float4*)&FI[off];
      float4 sv4 = *(const float4*)&SV[off];
      float4 w0 = *(const float4*)&W0[off];
      float4 w1 = *(const float4*)&W1[off];
      float4 w2 = *(const float4*)&W2[off];
      float4 w3 = *(const float4*)&W3[off];
      float4 w4 = *(const float4*)&W4[off];
      float4 w5 = *(const float4*)&W5[off];
      float4 qp = fi4*w0 + sv4*w1;
      float4 g2 = sv4*(fi4*w2 + sv4*w4);
      float4 g3 = sv4*(fi4*w3 + sv4*w5);
      stb4(&QPb[e*72 + off], qp);
      stb4(&G2b[e*72 + off], g2);
      stb4(&G3b[e*72 + off], g3);
    }
  }
  if (t < 128) {
    int e = t & 63, dh = t >> 6;
    const float* W6 = Wt + 6*4096 + e*64 + dh*32;
    const float* fip = FI + dh*32;
    const float* svp = SV + dh*32;
    float a = 0.f;
#pragma unroll
    for (int dd = 0; dd < 32; ++dd) {
      float sd = svp[dd];
      a += sd*sd*fip[dd]*W6[dd];
    }
    C0P[dh*64 + e] = a;
  }
  __syncthreads();

  if (w < 2) {
    const short* G = w ? G3b : G2b;
    float* DST = w ? JCf : KCf;
    short8 Bf[4][2];
#pragma unroll
    for (int n = 0; n < 4; ++n)
#pragma unroll
      for (int s2 = 0; s2 < 2; ++s2)
        Bf[n][s2] = *(const short8*)&G[(n*16 + col)*72 + s2*32 + quad*8];
#pragma unroll
    for (int m = 0; m < 2; ++m) {
      short8 A0 = *(const short8*)&Fb[(m*16 + col)*72 + quad*8];
      short8 A1 = *(const short8*)&Fb[(m*16 + col)*72 + 32 + quad*8];
#pragma unroll
      for (int n = 0; n < 4; ++n) {
        f32x4 z = {0.f, 0.f, 0.f, 0.f};
        f32x4 ac = mfma_bf16(A1, Bf[n][1], mfma_bf16(A0, Bf[n][0], z));
#pragma unroll
        for (int r = 0; r < 4; ++r)
          DST[(m*16 + quad*4 + r)*68 + n*16 + col] = ac[r];
      }
    }
  } else if (w == 2) {
    C0[l] = C0P[l] + C0P[64 + l] + t7c[b*64 + l];
  }
  __syncthreads();

  float c0v[4];
#pragma unroll
  for (int n = 0; n < 4; ++n) c0v[n] = C0[n*16 + col];
  float jcq[8][4];
#pragma unroll
  for (int jj = 0; jj < 8; ++jj)
#pragma unroll
    for (int n = 0; n < 4; ++n)
      jcq[jj][n] = JCf[(w*8 + jj)*68 + n*16 + col] + c0v[n];
  float kcv[2][4][4];
#pragma unroll
  for (int kb2 = 0; kb2 < 2; ++kb2)
#pragma unroll
    for (int r = 0; r < 4; ++r)
#pragma unroll
      for (int n = 0; n < 4; ++n)
        kcv[kb2][r][n] = KCf[(kb2*16 + quad*4 + r)*68 + n*16 + col];
  short8 Bq[4][2];
#pragma unroll
  for (int n = 0; n < 4; ++n)
#pragma unroll
    for (int s2 = 0; s2 < 2; ++s2)
      Bq[n][s2] = *(const short8*)&QPb[(n*16 + col)*72 + s2*32 + quad*8];

  float sum[4] = {0.f, 0.f, 0.f, 0.f};
  union SU { short8 v; unsigned int u[4]; };

#pragma unroll
  for (int mi = 0; mi < 16; ++mi) {
    const int jj = mi >> 1, kb2 = mi & 1;
    const float* fj = &Fm[(w*8 + jj)*68 + quad*8];
    const float* fk = &Fm[(kb2*16 + col)*68 + quad*8];
    float4 ja0 = *(const float4*)(fj);
    float4 ja1 = *(const float4*)(fj + 4);
    float4 jb0 = *(const float4*)(fj + 32);
    float4 jb1 = *(const float4*)(fj + 36);
    float4 ka0 = *(const float4*)(fk);
    float4 ka1 = *(const float4*)(fk + 4);
    float4 kb0 = *(const float4*)(fk + 32);
    float4 kb1 = *(const float4*)(fk + 36);
    SU A0, A1;
    A0.u[0] = pk2(ja0.x*ka0.x, ja0.y*ka0.y);
    A0.u[1] = pk2(ja0.z*ka0.z, ja0.w*ka0.w);
    A0.u[2] = pk2(ja1.x*ka1.x, ja1.y*ka1.y);
    A0.u[3] = pk2(ja1.z*ka1.z, ja1.w*ka1.w);
    A1.u[0] = pk2(jb0.x*kb0.x, jb0.y*kb0.y);
    A1.u[1] = pk2(jb0.z*kb0.z, jb0.w*kb0.w);
    A1.u[2] = pk2(jb1.x*kb1.x, jb1.y*kb1.y);
    A1.u[3] = pk2(jb1.z*kb1.z, jb1.w*kb1.w);
    f32x4 ac[4];
#pragma unroll
    for (int n = 0; n < 4; ++n) {
      f32x4 z = {0.f, 0.f, 0.f, 0.f};
      ac[n] = mfma_bf16(A1.v, Bq[n][1], mfma_bf16(A0.v, Bq[n][0], z));
    }
#pragma unroll
    for (int n = 0; n < 4; ++n)
#pragma unroll
      for (int r = 0; r < 4; ++r) {
        float v = ac[n][r] + kcv[kb2][r][n] + jcq[jj][n];
        sum[n] += fmaxf(v, 0.f);
      }
  }

#pragma unroll
  for (int n = 0; n < 4; ++n) {
    float v = sum[n];
    v += __shfl_xor(v, 16, 64);
    v += __shfl_xor(v, 32, 64);
    if (l < 16) RED[w*64 + n*16 + l] = v;
  }
  __syncthreads();
  if (t < 64) {
    float tot = RED[t] + RED[64 + t] + RED[128 + t] + RED[192 + t];
    atomicAdd(&x8[b*64 + t], tot);
  }
}

// ---------------- k6: x9 = relu(x8/K^3); out = x9 @ out_w.T + out_b ----------------
__global__ __launch_bounds__(64) void k6_out(const float* __restrict__ x8,
    const float* __restrict__ ow, const float* __restrict__ ob,
    float* __restrict__ out) {
  const int bb = blockIdx.x, t = threadIdx.x;
  float v = fmaxf(x8[bb*64 + t] * (1.f/32768.f), 0.f) * ow[t];
#pragma unroll
  for (int off = 32; off > 0; off >>= 1) v += __shfl_down(v, off, 64);
  if (t == 0) out[bb] = v + ob[0];
}

extern "C" void kernel_launch(void* const* d_in, const int* in_sizes, int n_in,
                              void* d_out, int out_size, void* d_ws, size_t ws_size,
                              hipStream_t stream) {
  const float* x   = (const float*)d_in[0];
  const float* c1w = (const float*)d_in[1];
  const float* c1b = (const float*)d_in[2];
  const float* c2w = (const float*)d_in[3];
  const float* c2b = (const float*)d_in[4];
  const float* fcw = (const float*)d_in[5];
  const float* fcb = (const float*)d_in[6];
  const float* eqw = (const float*)d_in[7];
  const float* eqb = (const float*)d_in[8];
  const float* ow  = (const float*)d_in[9];
  const float* ob  = (const float*)d_in[10];
  float* out = (float*)d_out;

  float* ws   = (float*)d_ws;
  float* h1   = ws;                      // 512*6272
  float* h2   = h1 + 512*6272;           // 512*3136
  float* feat = h2 + 512*3136;           // 512*64
  float* s    = feat + 512*64;           // 16*64
  float* t7c  = s + 1024;                // 16*64
  float* x8   = t7c + 1024;              // 16*64
  float* Wt   = x8 + 1024;               // 8*64*64

  hipLaunchKernelGGL(k1_conv1, dim3(512), dim3(256), 0, stream, x, c1w, c1b, h1);
  hipLaunchKernelGGL(k2_mfma,  dim3(512), dim3(256), 0, stream, h1, c2w, c2b, h2);
  hipLaunchKernelGGL(k3_fc,    dim3(128), dim3(256), 0, stream, h2, fcw, fcb, feat);
  hipLaunchKernelGGL(k4_wt,    dim3(8),   dim3(256), 0, stream, eqw, Wt);
  hipLaunchKernelGGL(k4_prep,  dim3(16),  dim3(64),  0, stream, feat, Wt, eqb, s, t7c, x8);
  hipLaunchKernelGGL(k5_mfma,  dim3(32, 16), dim3(256), 0, stream, feat, s, Wt, t7c, x8);
  hipLaunchKernelGGL(k6_out,   dim3(16),  dim3(64),  0, stream, x8, ow, ob, out);
}